// Round 4
// baseline (217.084 us; speedup 1.0000x reference)
//
#include <hip/hip_runtime.h>
#include <math.h>

#define BB 8
#define CC 3
#define HH 256
#define WW 256
#define KSZ 37
#define PD 18

#define DWT_OFF 0
#define GAB_OFF (8*12*128*128)                 /* 1572864 */
#define FFT_OFF (GAB_OFF + 8*54*256*256)       /* 29884416 */

#define PSTRIDE 88   /* patch row stride in bf16 elems */

typedef short bf16x8 __attribute__((ext_vector_type(8)));
typedef float f32x16 __attribute__((ext_vector_type(16)));

__device__ __forceinline__ unsigned f2bf(float f) {
  unsigned u = __float_as_uint(f);
  return (u + 0x7fffu + ((u >> 16) & 1u)) >> 16;   // RNE bf16
}

// ------------------------------------------------- filter prep: 8 shifted
// bf16 copies, Wsh[s][ky][32 m][48 kx'], zero-padded (m>=18 or kx'-s outside)
__global__ __launch_bounds__(256) void prep_wsh_kernel(
    const float* __restrict__ wk, ushort* __restrict__ wsh) {
  int idx = blockIdx.x * 256 + threadIdx.x;      // 8*37*32*48 = 454656
  if (idx >= 454656) return;
  int kx = idx % 48; int tmp = idx / 48;
  int m = tmp % 32; tmp /= 32;
  int ky = tmp % 37; int s = tmp / 37;
  int kk = kx - s;
  float v = 0.0f;
  if (m < 18 && kk >= 0 && kk < 37) v = wk[(m * 37 + ky) * 37 + kk];
  wsh[idx] = (ushort)f2bf(v);
}

// ------------------------------------------------- Gabor conv via MFMA
// Block: 512 thr (8 waves), tile 32y x 32x, all 18 filters.
// Wave w owns columns {w, w+8, w+16, w+24}; uses Wsh shift s=w.
// ky loop: explicit ping-pong software pipeline (prefetch ky+1 before
// MFMAs of ky) so global A-loads / LDS B-loads never stall the MFMA pipe.
#define LOAD_A(S, P) \
  a0##S = *reinterpret_cast<const bf16x8*>(P); \
  a1##S = *reinterpret_cast<const bf16x8*>((P) + 16); \
  a2##S = *reinterpret_cast<const bf16x8*>((P) + 32);
#define LOAD_B(S, P) \
  r0##S = *reinterpret_cast<const bf16x8*>(P); \
  r1##S = *reinterpret_cast<const bf16x8*>((P) + 8); \
  r2##S = *reinterpret_cast<const bf16x8*>((P) + 16); \
  r3##S = *reinterpret_cast<const bf16x8*>((P) + 24); \
  r4##S = *reinterpret_cast<const bf16x8*>((P) + 32); \
  r5##S = *reinterpret_cast<const bf16x8*>((P) + 40); \
  r6##S = *reinterpret_cast<const bf16x8*>((P) + 48); \
  r7##S = *reinterpret_cast<const bf16x8*>((P) + 56);
#define MFMA_GROUP(S) \
  acc0 = __builtin_amdgcn_mfma_f32_32x32x16_bf16(a0##S, r0##S, acc0, 0, 0, 0); \
  acc1 = __builtin_amdgcn_mfma_f32_32x32x16_bf16(a0##S, r1##S, acc1, 0, 0, 0); \
  acc2 = __builtin_amdgcn_mfma_f32_32x32x16_bf16(a0##S, r2##S, acc2, 0, 0, 0); \
  acc3 = __builtin_amdgcn_mfma_f32_32x32x16_bf16(a0##S, r3##S, acc3, 0, 0, 0); \
  acc0 = __builtin_amdgcn_mfma_f32_32x32x16_bf16(a1##S, r2##S, acc0, 0, 0, 0); \
  acc1 = __builtin_amdgcn_mfma_f32_32x32x16_bf16(a1##S, r3##S, acc1, 0, 0, 0); \
  acc2 = __builtin_amdgcn_mfma_f32_32x32x16_bf16(a1##S, r4##S, acc2, 0, 0, 0); \
  acc3 = __builtin_amdgcn_mfma_f32_32x32x16_bf16(a1##S, r5##S, acc3, 0, 0, 0); \
  acc0 = __builtin_amdgcn_mfma_f32_32x32x16_bf16(a2##S, r4##S, acc0, 0, 0, 0); \
  acc1 = __builtin_amdgcn_mfma_f32_32x32x16_bf16(a2##S, r5##S, acc1, 0, 0, 0); \
  acc2 = __builtin_amdgcn_mfma_f32_32x32x16_bf16(a2##S, r6##S, acc2, 0, 0, 0); \
  acc3 = __builtin_amdgcn_mfma_f32_32x32x16_bf16(a2##S, r7##S, acc3, 0, 0, 0);

__global__ __launch_bounds__(512) void gabor_mfma_kernel(
    const float* __restrict__ x, const ushort* __restrict__ wsh,
    float* __restrict__ out) {
  __shared__ unsigned patchU[68 * (PSTRIDE / 2)];  // 68 rows x 88 bf16
  __shared__ float cbuf[4 * 32 * 33];              // C transpose buffer

  const int tid = threadIdx.x;
  const int tileX = (blockIdx.x & 7) * 32;
  const int tileY = (blockIdx.x >> 3) * 32;
  const int cin = blockIdx.y, b = blockIdx.z;
  const float* xp = x + (size_t)(b * CC + cin) * (HH * WW);

  // ---- stage 68x88 bf16 patch, zero borders and the 68..87 tail
  for (int idx = tid; idx < 68 * (PSTRIDE / 2); idx += 512) {
    int r = idx / (PSTRIDE / 2), dc = idx - r * (PSTRIDE / 2);
    int gy = tileY + r - PD;
    int gx0 = tileX + 2 * dc - PD;
    float v0 = 0.0f, v1 = 0.0f;
    if ((unsigned)gy < 256u) {
      if ((unsigned)gx0 < 256u)       v0 = xp[gy * WW + gx0];
      if ((unsigned)(gx0 + 1) < 256u) v1 = xp[gy * WW + gx0 + 1];
    }
    patchU[idx] = f2bf(v0) | (f2bf(v1) << 16);
  }
  __syncthreads();

  const int w  = tid >> 6;
  const int l  = tid & 63;
  const int n  = l & 31;        // B col = pixel y offset; A row = filter
  const int hi = l >> 5;        // k-half selector

  f32x16 acc0 = {0.f,0.f,0.f,0.f,0.f,0.f,0.f,0.f,0.f,0.f,0.f,0.f,0.f,0.f,0.f,0.f};
  f32x16 acc1 = acc0, acc2 = acc0, acc3 = acc0;

  const ushort* patchS = reinterpret_cast<const ushort*>(patchU);
  const ushort* ap = wsh + (size_t)w * (37 * 32 * 48) + (size_t)n * 48 + hi * 8;
  const ushort* bp = patchS + (size_t)n * PSTRIDE + hi * 8;

  bf16x8 a0A, a1A, a2A, r0A, r1A, r2A, r3A, r4A, r5A, r6A, r7A;
  bf16x8 a0B, a1B, a2B, r0B, r1B, r2B, r3B, r4B, r5B, r6B, r7B;

  LOAD_A(A, ap)
  LOAD_B(A, bp)
  for (int kp = 0; kp < 18; ++kp) {
    // prefetch ky = 2kp+1, then compute ky = 2kp
    LOAD_A(B, ap + 1536)
    LOAD_B(B, bp + PSTRIDE)
    MFMA_GROUP(A)
    // prefetch ky = 2kp+2 (kp=17 -> ky=36, valid), compute ky = 2kp+1
    LOAD_A(A, ap + 3072)
    LOAD_B(A, bp + 2 * PSTRIDE)
    MFMA_GROUP(B)
    ap += 3072;
    bp += 2 * PSTRIDE;
  }
  MFMA_GROUP(A)                                    // ky = 36
  __syncthreads();

  // ---- epilogue: transpose C through LDS, coalesced stores
  // C row f' = (reg&3) + 8*(reg>>2) + 4*hi ; col = n (pixel y)
  float* outb = out + GAB_OFF + (size_t)(b * 54 + cin * 18) * (HH * WW);
#pragma unroll
  for (int g = 0; g < 5; ++g) {                  // f' groups [4g,4g+4), f'<20
    if (hi == (g & 1)) {
      const int rq = g >> 1;
#pragma unroll
      for (int q = 0; q < 4; ++q) {
        const int e = 4 * rq + q;
        float* crow = &cbuf[(q * 32 + n) * 33 + w];
        crow[0]  = acc0[e];
        crow[8]  = acc1[e];
        crow[16] = acc2[e];
        crow[24] = acc3[e];
      }
    }
    __syncthreads();
#pragma unroll
    for (int it = 0; it < 8; ++it) {
      int idx = tid + it * 512;                  // 4096 = 4f x 32y x 32x
      int xo = idx & 31, yo = (idx >> 5) & 31, q = idx >> 10;
      int f = 4 * g + q;
      if (f < 18)
        outb[(size_t)f * (HH * WW) + (size_t)(tileY + yo) * WW + tileX + xo] =
            cbuf[(q * 32 + yo) * 33 + xo];
    }
    __syncthreads();
  }
}

// ---------------------------------------------------------------- Haar DWT
__global__ __launch_bounds__(256) void haar_dwt_kernel(
    const float* __restrict__ x, float* __restrict__ out) {
  int idx = blockIdx.x * 256 + threadIdx.x;
  if (idx >= BB * CC * 128 * 128) return;
  int j  = idx & 127;
  int i  = (idx >> 7) & 127;
  int bc = idx >> 14;
  const float* xp = x + (size_t)bc * (HH * WW);
  float2 top = *reinterpret_cast<const float2*>(&xp[(2 * i) * WW + 2 * j]);
  float2 bot = *reinterpret_cast<const float2*>(&xp[(2 * i + 1) * WW + 2 * j]);
  float a = top.x, b = top.y, c = bot.x, d = bot.y;
  int bI = bc / 3, cI = bc % 3;
  float* op = out + DWT_OFF + ((size_t)(bI * 12 + cI * 4) * 128 + i) * 128 + j;
  op[0]     = (a + b + c + d) * 0.5f;
  op[16384] = (a + b - c - d) * 0.5f;
  op[32768] = (a - b + c - d) * 0.5f;
  op[49152] = (a - b - c + d) * 0.5f;
}

// ---------------------------------------------------------------- FFT pass A
// 64-thread block per row; twiddles from a 128-entry LDS table
// (tw[k] = exp(-2*pi*i*k/256); stage-s butterfly p uses tw[p << (8-s)]).
__global__ __launch_bounds__(64) void fft_rows_kernel(
    const float* __restrict__ x, float* __restrict__ stg) {
  __shared__ float re[256], im[256], twr[128], twi[128];
  const int rowid = blockIdx.x;
  const float* xr = x + (size_t)rowid * 256;
  const int t = threadIdx.x;

#pragma unroll
  for (int q = 0; q < 2; ++q) {
    int k = t + q * 64;
    float sn, cs;
    sincosf(-2.0f * (float)M_PI * (float)k / 256.0f, &sn, &cs);
    twr[k] = cs; twi[k] = sn;
  }
#pragma unroll
  for (int q = 0; q < 4; ++q) {
    int i = t + q * 64;
    int br = __brev((unsigned)i) >> 24;
    re[br] = xr[i];
    im[br] = 0.0f;
  }
  __syncthreads();

  for (int s = 1; s <= 8; ++s) {
    int half = 1 << (s - 1);
    int sh = 8 - s;
#pragma unroll
    for (int q = 0; q < 2; ++q) {
      int j = t + q * 64;
      int g = j >> (s - 1);
      int p = j & (half - 1);
      int i1 = (g << s) + p;
      int i2 = i1 + half;
      float cs = twr[p << sh], sn = twi[p << sh];
      float r2 = re[i2], m2 = im[i2];
      float tr = r2 * cs - m2 * sn;
      float ti = r2 * sn + m2 * cs;
      float r1 = re[i1], m1 = im[i1];
      re[i2] = r1 - tr; im[i2] = m1 - ti;
      re[i1] = r1 + tr; im[i1] = m1 + ti;
    }
    __syncthreads();
  }

  float* sr = stg + (size_t)rowid * 258;
#pragma unroll
  for (int q = 0; q < 3; ++q) {
    int k = t + q * 64;
    if (k <= 128) {
      sr[2 * k]     = re[k];
      sr[2 * k + 1] = im[k];
    }
  }
}

// ---------------------------------------------------------------- FFT pass B
__global__ __launch_bounds__(64) void fft_cols_kernel(
    const float* __restrict__ stg, float* __restrict__ outf) {
  const int k  = blockIdx.x & 255;
  const int bc = blockIdx.x >> 8;
  const int b  = bc / 3;
  const int c  = bc - b * 3;
  const int t  = threadIdx.x;
  float* magp = outf + (size_t)(b * 6 + c) * (HH * WW);
  float* php  = outf + (size_t)(b * 6 + c + 3) * (HH * WW);

  if (k >= 129) {
#pragma unroll
    for (int q = 0; q < 4; ++q) {
      int u = t + q * 64;
      magp[(size_t)u * WW + k] = 0.0f;
      php[(size_t)u * WW + k]  = 0.0f;
    }
    return;
  }

  __shared__ float re[256], im[256], twr[128], twi[128];
  const float* sp = stg + (size_t)bc * (256 * 258);
#pragma unroll
  for (int q = 0; q < 2; ++q) {
    int kk = t + q * 64;
    float sn, cs;
    sincosf(-2.0f * (float)M_PI * (float)kk / 256.0f, &sn, &cs);
    twr[kk] = cs; twi[kk] = sn;
  }
#pragma unroll
  for (int q = 0; q < 4; ++q) {
    int y = t + q * 64;
    int br = __brev((unsigned)y) >> 24;
    re[br] = sp[(size_t)y * 258 + 2 * k];
    im[br] = sp[(size_t)y * 258 + 2 * k + 1];
  }
  __syncthreads();

  for (int s = 1; s <= 8; ++s) {
    int half = 1 << (s - 1);
    int sh = 8 - s;
#pragma unroll
    for (int q = 0; q < 2; ++q) {
      int j = t + q * 64;
      int g = j >> (s - 1);
      int p = j & (half - 1);
      int i1 = (g << s) + p;
      int i2 = i1 + half;
      float cs = twr[p << sh], sn = twi[p << sh];
      float r2 = re[i2], m2 = im[i2];
      float tr = r2 * cs - m2 * sn;
      float ti = r2 * sn + m2 * cs;
      float r1 = re[i1], m1 = im[i1];
      re[i2] = r1 - tr; im[i2] = m1 - ti;
      re[i1] = r1 + tr; im[i1] = m1 + ti;
    }
    __syncthreads();
  }

  const float scale = 1.0f / 256.0f;
#pragma unroll
  for (int q = 0; q < 4; ++q) {
    int u = t + q * 64;
    float r = re[u], m = im[u];
    magp[(size_t)u * WW + k] = sqrtf(r * r + m * m) * scale;
    php[(size_t)u * WW + k]  = atan2f(m, r);
  }
}

// ----------------------------------------------------------------
extern "C" void kernel_launch(void* const* d_in, const int* in_sizes, int n_in,
                              void* d_out, int out_size, void* d_ws, size_t ws_size,
                              hipStream_t stream) {
  const float* x  = (const float*)d_in[0];
  const float* wk = (const float*)d_in[1];
  float* out = (float*)d_out;

  // Scratch regions inside d_out (stream-serialized, overwritten later):
  //  - shifted bf16 filters in the DWT region (DWT kernel runs last)
  //  - FFT row staging in the gabor region (conv runs after fft_cols)
  ushort* wsh = (ushort*)(out + DWT_OFF);        // 909 KB
  float*  stg = out + GAB_OFF;

  prep_wsh_kernel<<<dim3(1776), dim3(256), 0, stream>>>(wk, wsh);
  fft_rows_kernel<<<dim3(BB * CC * HH), dim3(64), 0, stream>>>(x, stg);
  fft_cols_kernel<<<dim3(BB * CC * WW), dim3(64), 0, stream>>>(stg, out + FFT_OFF);
  gabor_mfma_kernel<<<dim3(64, CC, BB), dim3(512), 0, stream>>>(x, wsh, out);
  haar_dwt_kernel<<<dim3(1536), dim3(256), 0, stream>>>(x, out);
}

// Round 5
// 199.559 us; speedup vs baseline: 1.0878x; 1.0878x over previous
//
#include <hip/hip_runtime.h>
#include <math.h>

#define BB 8
#define CC 3
#define HH 256
#define WW 256
#define KSZ 37
#define PD 18

#define DWT_OFF 0
#define GAB_OFF (8*12*128*128)                 /* 1572864 */
#define FFT_OFF (GAB_OFF + 8*54*256*256)       /* 29884416 */

#define PSTRIDE 88   /* patch row stride in bf16 elems */

typedef short bf16x8 __attribute__((ext_vector_type(8)));
typedef float f32x16 __attribute__((ext_vector_type(16)));

__device__ __forceinline__ unsigned f2bf(float f) {
  unsigned u = __float_as_uint(f);
  return (u + 0x7fffu + ((u >> 16) & 1u)) >> 16;   // RNE bf16
}

// ------------------------------------------------- filter prep: 8 shifted
// bf16 copies, Wsh[s][ky][32 m][48 kx'], zero-padded (m>=18 or kx'-s outside)
__global__ __launch_bounds__(256) void prep_wsh_kernel(
    const float* __restrict__ wk, ushort* __restrict__ wsh) {
  int idx = blockIdx.x * 256 + threadIdx.x;      // 8*37*32*48 = 454656
  if (idx >= 454656) return;
  int kx = idx % 48; int tmp = idx / 48;
  int m = tmp % 32; tmp /= 32;
  int ky = tmp % 37; int s = tmp / 37;
  int kk = kx - s;
  float v = 0.0f;
  if (m < 18 && kk >= 0 && kk < 37) v = wk[(m * 37 + ky) * 37 + kk];
  wsh[idx] = (ushort)f2bf(v);
}

// ------------------------------------------------- Gabor conv via MFMA
// Block: 512 thr (8 waves), tile 32y x 32x, all 18 filters.
// Wave w owns columns {w, w+8, w+16, w+24}; uses Wsh shift s=w.
// Anti-convoy: wave w processes ky in rotated order starting at 5*w, so at
// any instant some waves are loading while others run MFMAs (pipe overlap).
#define CONV_BODY \
  { \
    bf16x8 a0 = *reinterpret_cast<const bf16x8*>(ap); \
    bf16x8 a1 = *reinterpret_cast<const bf16x8*>(ap + 16); \
    bf16x8 a2 = *reinterpret_cast<const bf16x8*>(ap + 32); \
    bf16x8 r0 = *reinterpret_cast<const bf16x8*>(bp); \
    bf16x8 r1 = *reinterpret_cast<const bf16x8*>(bp + 8); \
    bf16x8 r2 = *reinterpret_cast<const bf16x8*>(bp + 16); \
    bf16x8 r3 = *reinterpret_cast<const bf16x8*>(bp + 24); \
    bf16x8 r4 = *reinterpret_cast<const bf16x8*>(bp + 32); \
    bf16x8 r5 = *reinterpret_cast<const bf16x8*>(bp + 40); \
    bf16x8 r6 = *reinterpret_cast<const bf16x8*>(bp + 48); \
    bf16x8 r7 = *reinterpret_cast<const bf16x8*>(bp + 56); \
    __builtin_amdgcn_s_setprio(1); \
    acc0 = __builtin_amdgcn_mfma_f32_32x32x16_bf16(a0, r0, acc0, 0, 0, 0); \
    acc1 = __builtin_amdgcn_mfma_f32_32x32x16_bf16(a0, r1, acc1, 0, 0, 0); \
    acc2 = __builtin_amdgcn_mfma_f32_32x32x16_bf16(a0, r2, acc2, 0, 0, 0); \
    acc3 = __builtin_amdgcn_mfma_f32_32x32x16_bf16(a0, r3, acc3, 0, 0, 0); \
    acc0 = __builtin_amdgcn_mfma_f32_32x32x16_bf16(a1, r2, acc0, 0, 0, 0); \
    acc1 = __builtin_amdgcn_mfma_f32_32x32x16_bf16(a1, r3, acc1, 0, 0, 0); \
    acc2 = __builtin_amdgcn_mfma_f32_32x32x16_bf16(a1, r4, acc2, 0, 0, 0); \
    acc3 = __builtin_amdgcn_mfma_f32_32x32x16_bf16(a1, r5, acc3, 0, 0, 0); \
    acc0 = __builtin_amdgcn_mfma_f32_32x32x16_bf16(a2, r4, acc0, 0, 0, 0); \
    acc1 = __builtin_amdgcn_mfma_f32_32x32x16_bf16(a2, r5, acc1, 0, 0, 0); \
    acc2 = __builtin_amdgcn_mfma_f32_32x32x16_bf16(a2, r6, acc2, 0, 0, 0); \
    acc3 = __builtin_amdgcn_mfma_f32_32x32x16_bf16(a2, r7, acc3, 0, 0, 0); \
    __builtin_amdgcn_s_setprio(0); \
    ap += 1536; \
    bp += PSTRIDE; \
  }

__global__ __launch_bounds__(512) void gabor_mfma_kernel(
    const float* __restrict__ x, const ushort* __restrict__ wsh,
    float* __restrict__ out) {
  __shared__ unsigned patchU[68 * (PSTRIDE / 2)];  // 68 rows x 88 bf16
  __shared__ float cbuf[4 * 32 * 33];              // C transpose buffer

  const int tid = threadIdx.x;
  const int tileX = (blockIdx.x & 7) * 32;
  const int tileY = (blockIdx.x >> 3) * 32;
  const int cin = blockIdx.y, b = blockIdx.z;
  const float* xp = x + (size_t)(b * CC + cin) * (HH * WW);

  // ---- stage 68x88 bf16 patch, zero borders and the 68..87 tail
  for (int idx = tid; idx < 68 * (PSTRIDE / 2); idx += 512) {
    int r = idx / (PSTRIDE / 2), dc = idx - r * (PSTRIDE / 2);
    int gy = tileY + r - PD;
    int gx0 = tileX + 2 * dc - PD;
    float v0 = 0.0f, v1 = 0.0f;
    if ((unsigned)gy < 256u) {
      if ((unsigned)gx0 < 256u)       v0 = xp[gy * WW + gx0];
      if ((unsigned)(gx0 + 1) < 256u) v1 = xp[gy * WW + gx0 + 1];
    }
    patchU[idx] = f2bf(v0) | (f2bf(v1) << 16);
  }
  __syncthreads();

  const int w  = tid >> 6;
  const int l  = tid & 63;
  const int n  = l & 31;        // B col = pixel y offset; A row = filter
  const int hi = l >> 5;        // k-half selector

  f32x16 acc0 = {0.f,0.f,0.f,0.f,0.f,0.f,0.f,0.f,0.f,0.f,0.f,0.f,0.f,0.f,0.f,0.f};
  f32x16 acc1 = acc0, acc2 = acc0, acc3 = acc0;

  const ushort* patchS = reinterpret_cast<const ushort*>(patchU);
  const ushort* abase = wsh + (size_t)w * (37 * 32 * 48) + (size_t)n * 48 + hi * 8;
  const ushort* bbase = patchS + (size_t)n * PSTRIDE + hi * 8;

  const int start = w * 5;                         // 0,5,10,...,35 (<37)
  {
    const ushort* ap = abase + (size_t)start * 1536;
    const ushort* bp = bbase + (size_t)start * PSTRIDE;
    for (int ky = start; ky < 37; ++ky) CONV_BODY
  }
  {
    const ushort* ap = abase;
    const ushort* bp = bbase;
    for (int ky = 0; ky < start; ++ky) CONV_BODY
  }
  __syncthreads();

  // ---- epilogue: transpose C through LDS, coalesced stores
  // C row f' = (reg&3) + 8*(reg>>2) + 4*hi ; col = n (pixel y)
  float* outb = out + GAB_OFF + (size_t)(b * 54 + cin * 18) * (HH * WW);
#pragma unroll
  for (int g = 0; g < 5; ++g) {                  // f' groups [4g,4g+4), f'<20
    if (hi == (g & 1)) {
      const int rq = g >> 1;
#pragma unroll
      for (int q = 0; q < 4; ++q) {
        const int e = 4 * rq + q;
        float* crow = &cbuf[(q * 32 + n) * 33 + w];
        crow[0]  = acc0[e];
        crow[8]  = acc1[e];
        crow[16] = acc2[e];
        crow[24] = acc3[e];
      }
    }
    __syncthreads();
#pragma unroll
    for (int it = 0; it < 8; ++it) {
      int idx = tid + it * 512;                  // 4096 = 4f x 32y x 32x
      int xo = idx & 31, yo = (idx >> 5) & 31, q = idx >> 10;
      int f = 4 * g + q;
      if (f < 18)
        outb[(size_t)f * (HH * WW) + (size_t)(tileY + yo) * WW + tileX + xo] =
            cbuf[(q * 32 + yo) * 33 + xo];
    }
    __syncthreads();
  }
}

// ---------------------------------------------------------------- Haar DWT
__global__ __launch_bounds__(256) void haar_dwt_kernel(
    const float* __restrict__ x, float* __restrict__ out) {
  int idx = blockIdx.x * 256 + threadIdx.x;
  if (idx >= BB * CC * 128 * 128) return;
  int j  = idx & 127;
  int i  = (idx >> 7) & 127;
  int bc = idx >> 14;
  const float* xp = x + (size_t)bc * (HH * WW);
  float2 top = *reinterpret_cast<const float2*>(&xp[(2 * i) * WW + 2 * j]);
  float2 bot = *reinterpret_cast<const float2*>(&xp[(2 * i + 1) * WW + 2 * j]);
  float a = top.x, b = top.y, c = bot.x, d = bot.y;
  int bI = bc / 3, cI = bc % 3;
  float* op = out + DWT_OFF + ((size_t)(bI * 12 + cI * 4) * 128 + i) * 128 + j;
  op[0]     = (a + b + c + d) * 0.5f;
  op[16384] = (a + b - c - d) * 0.5f;
  op[32768] = (a - b + c - d) * 0.5f;
  op[49152] = (a - b - c + d) * 0.5f;
}

// ---------------------------------------------------------------- FFT pass A
// 64-thread block per row; twiddles from a 128-entry LDS table
// (tw[k] = exp(-2*pi*i*k/256); stage-s butterfly p uses tw[p << (8-s)]).
__global__ __launch_bounds__(64) void fft_rows_kernel(
    const float* __restrict__ x, float* __restrict__ stg) {
  __shared__ float re[256], im[256], twr[128], twi[128];
  const int rowid = blockIdx.x;
  const float* xr = x + (size_t)rowid * 256;
  const int t = threadIdx.x;

#pragma unroll
  for (int q = 0; q < 2; ++q) {
    int k = t + q * 64;
    float sn, cs;
    sincosf(-2.0f * (float)M_PI * (float)k / 256.0f, &sn, &cs);
    twr[k] = cs; twi[k] = sn;
  }
#pragma unroll
  for (int q = 0; q < 4; ++q) {
    int i = t + q * 64;
    int br = __brev((unsigned)i) >> 24;
    re[br] = xr[i];
    im[br] = 0.0f;
  }
  __syncthreads();

  for (int s = 1; s <= 8; ++s) {
    int half = 1 << (s - 1);
    int sh = 8 - s;
#pragma unroll
    for (int q = 0; q < 2; ++q) {
      int j = t + q * 64;
      int g = j >> (s - 1);
      int p = j & (half - 1);
      int i1 = (g << s) + p;
      int i2 = i1 + half;
      float cs = twr[p << sh], sn = twi[p << sh];
      float r2 = re[i2], m2 = im[i2];
      float tr = r2 * cs - m2 * sn;
      float ti = r2 * sn + m2 * cs;
      float r1 = re[i1], m1 = im[i1];
      re[i2] = r1 - tr; im[i2] = m1 - ti;
      re[i1] = r1 + tr; im[i1] = m1 + ti;
    }
    __syncthreads();
  }

  float* sr = stg + (size_t)rowid * 258;
#pragma unroll
  for (int q = 0; q < 3; ++q) {
    int k = t + q * 64;
    if (k <= 128) {
      sr[2 * k]     = re[k];
      sr[2 * k + 1] = im[k];
    }
  }
}

// ---------------------------------------------------------------- FFT pass B
__global__ __launch_bounds__(64) void fft_cols_kernel(
    const float* __restrict__ stg, float* __restrict__ outf) {
  const int k  = blockIdx.x & 255;
  const int bc = blockIdx.x >> 8;
  const int b  = bc / 3;
  const int c  = bc - b * 3;
  const int t  = threadIdx.x;
  float* magp = outf + (size_t)(b * 6 + c) * (HH * WW);
  float* php  = outf + (size_t)(b * 6 + c + 3) * (HH * WW);

  if (k >= 129) {
#pragma unroll
    for (int q = 0; q < 4; ++q) {
      int u = t + q * 64;
      magp[(size_t)u * WW + k] = 0.0f;
      php[(size_t)u * WW + k]  = 0.0f;
    }
    return;
  }

  __shared__ float re[256], im[256], twr[128], twi[128];
  const float* sp = stg + (size_t)bc * (256 * 258);
#pragma unroll
  for (int q = 0; q < 2; ++q) {
    int kk = t + q * 64;
    float sn, cs;
    sincosf(-2.0f * (float)M_PI * (float)kk / 256.0f, &sn, &cs);
    twr[kk] = cs; twi[kk] = sn;
  }
#pragma unroll
  for (int q = 0; q < 4; ++q) {
    int y = t + q * 64;
    int br = __brev((unsigned)y) >> 24;
    re[br] = sp[(size_t)y * 258 + 2 * k];
    im[br] = sp[(size_t)y * 258 + 2 * k + 1];
  }
  __syncthreads();

  for (int s = 1; s <= 8; ++s) {
    int half = 1 << (s - 1);
    int sh = 8 - s;
#pragma unroll
    for (int q = 0; q < 2; ++q) {
      int j = t + q * 64;
      int g = j >> (s - 1);
      int p = j & (half - 1);
      int i1 = (g << s) + p;
      int i2 = i1 + half;
      float cs = twr[p << sh], sn = twi[p << sh];
      float r2 = re[i2], m2 = im[i2];
      float tr = r2 * cs - m2 * sn;
      float ti = r2 * sn + m2 * cs;
      float r1 = re[i1], m1 = im[i1];
      re[i2] = r1 - tr; im[i2] = m1 - ti;
      re[i1] = r1 + tr; im[i1] = m1 + ti;
    }
    __syncthreads();
  }

  const float scale = 1.0f / 256.0f;
#pragma unroll
  for (int q = 0; q < 4; ++q) {
    int u = t + q * 64;
    float r = re[u], m = im[u];
    magp[(size_t)u * WW + k] = sqrtf(r * r + m * m) * scale;
    php[(size_t)u * WW + k]  = atan2f(m, r);
  }
}

// ----------------------------------------------------------------
extern "C" void kernel_launch(void* const* d_in, const int* in_sizes, int n_in,
                              void* d_out, int out_size, void* d_ws, size_t ws_size,
                              hipStream_t stream) {
  const float* x  = (const float*)d_in[0];
  const float* wk = (const float*)d_in[1];
  float* out = (float*)d_out;

  // Scratch regions inside d_out (stream-serialized, overwritten later):
  //  - shifted bf16 filters in the DWT region (DWT kernel runs last)
  //  - FFT row staging in the gabor region (conv runs after fft_cols)
  ushort* wsh = (ushort*)(out + DWT_OFF);        // 909 KB
  float*  stg = out + GAB_OFF;

  prep_wsh_kernel<<<dim3(1776), dim3(256), 0, stream>>>(wk, wsh);
  fft_rows_kernel<<<dim3(BB * CC * HH), dim3(64), 0, stream>>>(x, stg);
  fft_cols_kernel<<<dim3(BB * CC * WW), dim3(64), 0, stream>>>(stg, out + FFT_OFF);
  gabor_mfma_kernel<<<dim3(64, CC, BB), dim3(512), 0, stream>>>(x, wsh, out);
  haar_dwt_kernel<<<dim3(1536), dim3(256), 0, stream>>>(x, out);
}

// Round 6
// 193.456 us; speedup vs baseline: 1.1221x; 1.0316x over previous
//
#include <hip/hip_runtime.h>
#include <math.h>

#define BB 8
#define CC 3
#define HH 256
#define WW 256
#define KSZ 37
#define PD 18

#define DWT_OFF 0
#define GAB_OFF (8*12*128*128)                 /* 1572864 */
#define FFT_OFF (GAB_OFF + 8*54*256*256)       /* 29884416 */

#define PSTRIDE 88   /* patch row stride in bf16 elems */

typedef short bf16x8 __attribute__((ext_vector_type(8)));
typedef float f32x16 __attribute__((ext_vector_type(16)));

__device__ __forceinline__ unsigned f2bf(float f) {
  unsigned u = __float_as_uint(f);
  return (u + 0x7fffu + ((u >> 16) & 1u)) >> 16;   // RNE bf16
}

// ------------------------------------------------- filter prep, COALESCED
// wshc[s][ky][t][lane][8]: lane l holds A-row m=l&31, k-elems 16t+8*(l>>5)+j
// (exact mfma_32x32x16 A-fragment order, so conv's A-loads are 64x16B
// consecutive = fully coalesced). Zero-padded for m>=18 or kx-s outside.
__global__ __launch_bounds__(256) void prep_wshc_kernel(
    const float* __restrict__ wk, ushort* __restrict__ wshc) {
  int idx = blockIdx.x * 256 + threadIdx.x;      // 8*37*3*64*8 = 454656
  if (idx >= 454656) return;
  int j = idx & 7; int rest = idx >> 3;
  int l = rest & 63; rest >>= 6;
  int t = rest % 3; rest /= 3;
  int ky = rest % 37; int s = rest / 37;
  int m = l & 31, hi = l >> 5;
  int kk = 16 * t + 8 * hi + j - s;
  float v = 0.0f;
  if (m < 18 && kk >= 0 && kk < 37) v = wk[(m * 37 + ky) * 37 + kk];
  wshc[idx] = (ushort)f2bf(v);
}

// ------------------------------------------------- Gabor conv via MFMA
// Block: 512 thr (8 waves), tile 32y x 32x, all 18 filters.
// Wave w owns columns {w, w+8, w+16, w+24}; uses filter shift s=w.
// Structure identical to R3 (best so far) except A-loads now coalesced.
__global__ __launch_bounds__(512) void gabor_mfma_kernel(
    const float* __restrict__ x, const ushort* __restrict__ wshc,
    float* __restrict__ out) {
  __shared__ unsigned patchU[68 * (PSTRIDE / 2)];  // 68 rows x 88 bf16
  __shared__ float cbuf[4 * 32 * 33];              // C transpose buffer

  const int tid = threadIdx.x;
  const int tileX = (blockIdx.x & 7) * 32;
  const int tileY = (blockIdx.x >> 3) * 32;
  const int cin = blockIdx.y, b = blockIdx.z;
  const float* xp = x + (size_t)(b * CC + cin) * (HH * WW);

  // ---- stage 68x88 bf16 patch, zero borders and the 68..87 tail
  for (int idx = tid; idx < 68 * (PSTRIDE / 2); idx += 512) {
    int r = idx / (PSTRIDE / 2), dc = idx - r * (PSTRIDE / 2);
    int gy = tileY + r - PD;
    int gx0 = tileX + 2 * dc - PD;
    float v0 = 0.0f, v1 = 0.0f;
    if ((unsigned)gy < 256u) {
      if ((unsigned)gx0 < 256u)       v0 = xp[gy * WW + gx0];
      if ((unsigned)(gx0 + 1) < 256u) v1 = xp[gy * WW + gx0 + 1];
    }
    patchU[idx] = f2bf(v0) | (f2bf(v1) << 16);
  }
  __syncthreads();

  const int w  = tid >> 6;
  const int l  = tid & 63;
  const int n  = l & 31;        // B col = pixel y offset; A row = filter
  const int hi = l >> 5;        // k-half selector

  f32x16 acc0 = {0.f,0.f,0.f,0.f,0.f,0.f,0.f,0.f,0.f,0.f,0.f,0.f,0.f,0.f,0.f,0.f};
  f32x16 acc1 = acc0, acc2 = acc0, acc3 = acc0;

  const ushort* patchS = reinterpret_cast<const ushort*>(patchU);
  // lane-contiguous A: base + (ky*3 + t)*512 + l*8 ushorts
  const ushort* ap = wshc + (size_t)w * (37 * 3 * 512) + (size_t)l * 8;
  const ushort* bp = patchS + (size_t)n * PSTRIDE + hi * 8;

  for (int ky = 0; ky < 37; ++ky) {
    bf16x8 a0 = *reinterpret_cast<const bf16x8*>(ap);
    bf16x8 a1 = *reinterpret_cast<const bf16x8*>(ap + 512);
    bf16x8 a2 = *reinterpret_cast<const bf16x8*>(ap + 1024);
    bf16x8 r0 = *reinterpret_cast<const bf16x8*>(bp);
    bf16x8 r1 = *reinterpret_cast<const bf16x8*>(bp + 8);
    bf16x8 r2 = *reinterpret_cast<const bf16x8*>(bp + 16);
    bf16x8 r3 = *reinterpret_cast<const bf16x8*>(bp + 24);
    bf16x8 r4 = *reinterpret_cast<const bf16x8*>(bp + 32);
    bf16x8 r5 = *reinterpret_cast<const bf16x8*>(bp + 40);
    bf16x8 r6 = *reinterpret_cast<const bf16x8*>(bp + 48);
    bf16x8 r7 = *reinterpret_cast<const bf16x8*>(bp + 56);

    acc0 = __builtin_amdgcn_mfma_f32_32x32x16_bf16(a0, r0, acc0, 0, 0, 0);
    acc1 = __builtin_amdgcn_mfma_f32_32x32x16_bf16(a0, r1, acc1, 0, 0, 0);
    acc2 = __builtin_amdgcn_mfma_f32_32x32x16_bf16(a0, r2, acc2, 0, 0, 0);
    acc3 = __builtin_amdgcn_mfma_f32_32x32x16_bf16(a0, r3, acc3, 0, 0, 0);

    acc0 = __builtin_amdgcn_mfma_f32_32x32x16_bf16(a1, r2, acc0, 0, 0, 0);
    acc1 = __builtin_amdgcn_mfma_f32_32x32x16_bf16(a1, r3, acc1, 0, 0, 0);
    acc2 = __builtin_amdgcn_mfma_f32_32x32x16_bf16(a1, r4, acc2, 0, 0, 0);
    acc3 = __builtin_amdgcn_mfma_f32_32x32x16_bf16(a1, r5, acc3, 0, 0, 0);

    acc0 = __builtin_amdgcn_mfma_f32_32x32x16_bf16(a2, r4, acc0, 0, 0, 0);
    acc1 = __builtin_amdgcn_mfma_f32_32x32x16_bf16(a2, r5, acc1, 0, 0, 0);
    acc2 = __builtin_amdgcn_mfma_f32_32x32x16_bf16(a2, r6, acc2, 0, 0, 0);
    acc3 = __builtin_amdgcn_mfma_f32_32x32x16_bf16(a2, r7, acc3, 0, 0, 0);

    ap += 3 * 512;
    bp += PSTRIDE;
  }
  __syncthreads();

  // ---- epilogue: transpose C through LDS, coalesced stores
  // C row f' = (reg&3) + 8*(reg>>2) + 4*hi ; col = n (pixel y)
  float* outb = out + GAB_OFF + (size_t)(b * 54 + cin * 18) * (HH * WW);
#pragma unroll
  for (int g = 0; g < 5; ++g) {                  // f' groups [4g,4g+4), f'<20
    if (hi == (g & 1)) {
      const int rq = g >> 1;
#pragma unroll
      for (int q = 0; q < 4; ++q) {
        const int e = 4 * rq + q;
        float* crow = &cbuf[(q * 32 + n) * 33 + w];
        crow[0]  = acc0[e];
        crow[8]  = acc1[e];
        crow[16] = acc2[e];
        crow[24] = acc3[e];
      }
    }
    __syncthreads();
#pragma unroll
    for (int it = 0; it < 8; ++it) {
      int idx = tid + it * 512;                  // 4096 = 4f x 32y x 32x
      int xo = idx & 31, yo = (idx >> 5) & 31, q = idx >> 10;
      int f = 4 * g + q;
      if (f < 18)
        outb[(size_t)f * (HH * WW) + (size_t)(tileY + yo) * WW + tileX + xo] =
            cbuf[(q * 32 + yo) * 33 + xo];
    }
    __syncthreads();
  }
}

// ---------------------------------------------------------------- Haar DWT
__global__ __launch_bounds__(256) void haar_dwt_kernel(
    const float* __restrict__ x, float* __restrict__ out) {
  int idx = blockIdx.x * 256 + threadIdx.x;
  if (idx >= BB * CC * 128 * 128) return;
  int j  = idx & 127;
  int i  = (idx >> 7) & 127;
  int bc = idx >> 14;
  const float* xp = x + (size_t)bc * (HH * WW);
  float2 top = *reinterpret_cast<const float2*>(&xp[(2 * i) * WW + 2 * j]);
  float2 bot = *reinterpret_cast<const float2*>(&xp[(2 * i + 1) * WW + 2 * j]);
  float a = top.x, b = top.y, c = bot.x, d = bot.y;
  int bI = bc / 3, cI = bc % 3;
  float* op = out + DWT_OFF + ((size_t)(bI * 12 + cI * 4) * 128 + i) * 128 + j;
  op[0]     = (a + b + c + d) * 0.5f;
  op[16384] = (a + b - c - d) * 0.5f;
  op[32768] = (a - b + c - d) * 0.5f;
  op[49152] = (a - b - c + d) * 0.5f;
}

// ---------------------------------------------------------------- FFT pass A
// 64-thread block per row; twiddles from a 128-entry LDS table
// (tw[k] = exp(-2*pi*i*k/256); stage-s butterfly p uses tw[p << (8-s)]).
__global__ __launch_bounds__(64) void fft_rows_kernel(
    const float* __restrict__ x, float* __restrict__ stg) {
  __shared__ float re[256], im[256], twr[128], twi[128];
  const int rowid = blockIdx.x;
  const float* xr = x + (size_t)rowid * 256;
  const int t = threadIdx.x;

#pragma unroll
  for (int q = 0; q < 2; ++q) {
    int k = t + q * 64;
    float sn, cs;
    sincosf(-2.0f * (float)M_PI * (float)k / 256.0f, &sn, &cs);
    twr[k] = cs; twi[k] = sn;
  }
#pragma unroll
  for (int q = 0; q < 4; ++q) {
    int i = t + q * 64;
    int br = __brev((unsigned)i) >> 24;
    re[br] = xr[i];
    im[br] = 0.0f;
  }
  __syncthreads();

  for (int s = 1; s <= 8; ++s) {
    int half = 1 << (s - 1);
    int sh = 8 - s;
#pragma unroll
    for (int q = 0; q < 2; ++q) {
      int j = t + q * 64;
      int g = j >> (s - 1);
      int p = j & (half - 1);
      int i1 = (g << s) + p;
      int i2 = i1 + half;
      float cs = twr[p << sh], sn = twi[p << sh];
      float r2 = re[i2], m2 = im[i2];
      float tr = r2 * cs - m2 * sn;
      float ti = r2 * sn + m2 * cs;
      float r1 = re[i1], m1 = im[i1];
      re[i2] = r1 - tr; im[i2] = m1 - ti;
      re[i1] = r1 + tr; im[i1] = m1 + ti;
    }
    __syncthreads();
  }

  float* sr = stg + (size_t)rowid * 258;
#pragma unroll
  for (int q = 0; q < 3; ++q) {
    int k = t + q * 64;
    if (k <= 128) {
      sr[2 * k]     = re[k];
      sr[2 * k + 1] = im[k];
    }
  }
}

// ---------------------------------------------------------------- FFT pass B
__global__ __launch_bounds__(64) void fft_cols_kernel(
    const float* __restrict__ stg, float* __restrict__ outf) {
  const int k  = blockIdx.x & 255;
  const int bc = blockIdx.x >> 8;
  const int b  = bc / 3;
  const int c  = bc - b * 3;
  const int t  = threadIdx.x;
  float* magp = outf + (size_t)(b * 6 + c) * (HH * WW);
  float* php  = outf + (size_t)(b * 6 + c + 3) * (HH * WW);

  if (k >= 129) {
#pragma unroll
    for (int q = 0; q < 4; ++q) {
      int u = t + q * 64;
      magp[(size_t)u * WW + k] = 0.0f;
      php[(size_t)u * WW + k]  = 0.0f;
    }
    return;
  }

  __shared__ float re[256], im[256], twr[128], twi[128];
  const float* sp = stg + (size_t)bc * (256 * 258);
#pragma unroll
  for (int q = 0; q < 2; ++q) {
    int kk = t + q * 64;
    float sn, cs;
    sincosf(-2.0f * (float)M_PI * (float)kk / 256.0f, &sn, &cs);
    twr[kk] = cs; twi[kk] = sn;
  }
#pragma unroll
  for (int q = 0; q < 4; ++q) {
    int y = t + q * 64;
    int br = __brev((unsigned)y) >> 24;
    re[br] = sp[(size_t)y * 258 + 2 * k];
    im[br] = sp[(size_t)y * 258 + 2 * k + 1];
  }
  __syncthreads();

  for (int s = 1; s <= 8; ++s) {
    int half = 1 << (s - 1);
    int sh = 8 - s;
#pragma unroll
    for (int q = 0; q < 2; ++q) {
      int j = t + q * 64;
      int g = j >> (s - 1);
      int p = j & (half - 1);
      int i1 = (g << s) + p;
      int i2 = i1 + half;
      float cs = twr[p << sh], sn = twi[p << sh];
      float r2 = re[i2], m2 = im[i2];
      float tr = r2 * cs - m2 * sn;
      float ti = r2 * sn + m2 * cs;
      float r1 = re[i1], m1 = im[i1];
      re[i2] = r1 - tr; im[i2] = m1 - ti;
      re[i1] = r1 + tr; im[i1] = m1 + ti;
    }
    __syncthreads();
  }

  const float scale = 1.0f / 256.0f;
#pragma unroll
  for (int q = 0; q < 4; ++q) {
    int u = t + q * 64;
    float r = re[u], m = im[u];
    magp[(size_t)u * WW + k] = sqrtf(r * r + m * m) * scale;
    php[(size_t)u * WW + k]  = atan2f(m, r);
  }
}

// ----------------------------------------------------------------
extern "C" void kernel_launch(void* const* d_in, const int* in_sizes, int n_in,
                              void* d_out, int out_size, void* d_ws, size_t ws_size,
                              hipStream_t stream) {
  const float* x  = (const float*)d_in[0];
  const float* wk = (const float*)d_in[1];
  float* out = (float*)d_out;

  // Scratch regions inside d_out (stream-serialized, overwritten later):
  //  - coalesced bf16 filters in the DWT region (DWT kernel runs last)
  //  - FFT row staging in the gabor region (conv runs after fft_cols)
  ushort* wshc = (ushort*)(out + DWT_OFF);       // 909 KB
  float*  stg  = out + GAB_OFF;

  prep_wshc_kernel<<<dim3(1776), dim3(256), 0, stream>>>(wk, wshc);
  fft_rows_kernel<<<dim3(BB * CC * HH), dim3(64), 0, stream>>>(x, stg);
  fft_cols_kernel<<<dim3(BB * CC * WW), dim3(64), 0, stream>>>(stg, out + FFT_OFF);
  gabor_mfma_kernel<<<dim3(64, CC, BB), dim3(512), 0, stream>>>(x, wshc, out);
  haar_dwt_kernel<<<dim3(1536), dim3(256), 0, stream>>>(x, out);
}

// Round 7
// 189.949 us; speedup vs baseline: 1.1429x; 1.0185x over previous
//
#include <hip/hip_runtime.h>
#include <math.h>

#define BB 8
#define CC 3
#define HH 256
#define WW 256
#define KSZ 37
#define PD 18

#define DWT_OFF 0
#define GAB_OFF (8*12*128*128)                 /* 1572864 */
#define FFT_OFF (GAB_OFF + 8*54*256*256)       /* 29884416 */

#define PSTRIDE 88   /* patch row stride in bf16 elems */

typedef short bf16x8 __attribute__((ext_vector_type(8)));
typedef float f32x16 __attribute__((ext_vector_type(16)));

__device__ __forceinline__ unsigned f2bf(float f) {
  unsigned u = __float_as_uint(f);
  return (u + 0x7fffu + ((u >> 16) & 1u)) >> 16;   // RNE bf16
}

// ------------------------------------------------- filter prep, COALESCED
// wshc[s][ky][t][lane][8]: lane l holds A-row m=l&31, k-elems 16t+8*(l>>5)+j
__global__ __launch_bounds__(256) void prep_wshc_kernel(
    const float* __restrict__ wk, ushort* __restrict__ wshc) {
  int idx = blockIdx.x * 256 + threadIdx.x;      // 8*37*3*64*8 = 454656
  if (idx >= 454656) return;
  int j = idx & 7; int rest = idx >> 3;
  int l = rest & 63; rest >>= 6;
  int t = rest % 3; rest /= 3;
  int ky = rest % 37; int s = rest / 37;
  int m = l & 31, hi = l >> 5;
  int kk = 16 * t + 8 * hi + j - s;
  float v = 0.0f;
  if (m < 18 && kk >= 0 && kk < 37) v = wk[(m * 37 + ky) * 37 + kk];
  wshc[idx] = (ushort)f2bf(v);
}

// ------------------------------------------------- Gabor conv via MFMA
// 8 waves/block, tile 32y x 32x, 18 filters. Wave w: columns {w,w+8,w+16,w+24},
// filter shift s=w. ky loop: A-operand ping-pong prefetch (global/L2 latency is
// the serializer; B stays single-set — compiler's fine-grained lgkmcnt streams
// the 8 ds_read_b128 under the MFMA sequence).
#define LOAD_B_SET \
    r0 = *reinterpret_cast<const bf16x8*>(bp); \
    r1 = *reinterpret_cast<const bf16x8*>(bp + 8); \
    r2 = *reinterpret_cast<const bf16x8*>(bp + 16); \
    r3 = *reinterpret_cast<const bf16x8*>(bp + 24); \
    r4 = *reinterpret_cast<const bf16x8*>(bp + 32); \
    r5 = *reinterpret_cast<const bf16x8*>(bp + 40); \
    r6 = *reinterpret_cast<const bf16x8*>(bp + 48); \
    r7 = *reinterpret_cast<const bf16x8*>(bp + 56);
#define MFMA_GROUP(A0, A1, A2) \
    acc0 = __builtin_amdgcn_mfma_f32_32x32x16_bf16(A0, r0, acc0, 0, 0, 0); \
    acc1 = __builtin_amdgcn_mfma_f32_32x32x16_bf16(A0, r1, acc1, 0, 0, 0); \
    acc2 = __builtin_amdgcn_mfma_f32_32x32x16_bf16(A0, r2, acc2, 0, 0, 0); \
    acc3 = __builtin_amdgcn_mfma_f32_32x32x16_bf16(A0, r3, acc3, 0, 0, 0); \
    acc0 = __builtin_amdgcn_mfma_f32_32x32x16_bf16(A1, r2, acc0, 0, 0, 0); \
    acc1 = __builtin_amdgcn_mfma_f32_32x32x16_bf16(A1, r3, acc1, 0, 0, 0); \
    acc2 = __builtin_amdgcn_mfma_f32_32x32x16_bf16(A1, r4, acc2, 0, 0, 0); \
    acc3 = __builtin_amdgcn_mfma_f32_32x32x16_bf16(A1, r5, acc3, 0, 0, 0); \
    acc0 = __builtin_amdgcn_mfma_f32_32x32x16_bf16(A2, r4, acc0, 0, 0, 0); \
    acc1 = __builtin_amdgcn_mfma_f32_32x32x16_bf16(A2, r5, acc1, 0, 0, 0); \
    acc2 = __builtin_amdgcn_mfma_f32_32x32x16_bf16(A2, r6, acc2, 0, 0, 0); \
    acc3 = __builtin_amdgcn_mfma_f32_32x32x16_bf16(A2, r7, acc3, 0, 0, 0);

__global__ __launch_bounds__(512, 4) void gabor_mfma_kernel(
    const float* __restrict__ x, const ushort* __restrict__ wshc,
    float* __restrict__ out) {
  __shared__ unsigned patchU[68 * (PSTRIDE / 2)];  // 68 rows x 88 bf16
  __shared__ float cbuf[4 * 32 * 33];              // C transpose buffer

  const int tid = threadIdx.x;
  const int tileX = (blockIdx.x & 7) * 32;
  const int tileY = (blockIdx.x >> 3) * 32;
  const int cin = blockIdx.y, b = blockIdx.z;
  const float* xp = x + (size_t)(b * CC + cin) * (HH * WW);

  // ---- stage 68x88 bf16 patch, zero borders and the 68..87 tail
  for (int idx = tid; idx < 68 * (PSTRIDE / 2); idx += 512) {
    int r = idx / (PSTRIDE / 2), dc = idx - r * (PSTRIDE / 2);
    int gy = tileY + r - PD;
    int gx0 = tileX + 2 * dc - PD;
    float v0 = 0.0f, v1 = 0.0f;
    if ((unsigned)gy < 256u) {
      if ((unsigned)gx0 < 256u)       v0 = xp[gy * WW + gx0];
      if ((unsigned)(gx0 + 1) < 256u) v1 = xp[gy * WW + gx0 + 1];
    }
    patchU[idx] = f2bf(v0) | (f2bf(v1) << 16);
  }
  __syncthreads();

  const int w  = tid >> 6;
  const int l  = tid & 63;
  const int n  = l & 31;        // B col = pixel y offset; A row = filter
  const int hi = l >> 5;        // k-half selector

  f32x16 acc0 = {0.f,0.f,0.f,0.f,0.f,0.f,0.f,0.f,0.f,0.f,0.f,0.f,0.f,0.f,0.f,0.f};
  f32x16 acc1 = acc0, acc2 = acc0, acc3 = acc0;

  const ushort* patchS = reinterpret_cast<const ushort*>(patchU);
  const ushort* ap = wshc + (size_t)w * (37 * 3 * 512) + (size_t)l * 8;
  const ushort* bp = patchS + (size_t)n * PSTRIDE + hi * 8;

  bf16x8 aA0, aA1, aA2, aB0, aB1, aB2;
  bf16x8 r0, r1, r2, r3, r4, r5, r6, r7;

  aA0 = *reinterpret_cast<const bf16x8*>(ap);
  aA1 = *reinterpret_cast<const bf16x8*>(ap + 512);
  aA2 = *reinterpret_cast<const bf16x8*>(ap + 1024);

  for (int kp = 0; kp < 18; ++kp) {
    // even ky = 2kp: prefetch A(ky+1), compute with aA
    aB0 = *reinterpret_cast<const bf16x8*>(ap + 1536);
    aB1 = *reinterpret_cast<const bf16x8*>(ap + 2048);
    aB2 = *reinterpret_cast<const bf16x8*>(ap + 2560);
    LOAD_B_SET
    MFMA_GROUP(aA0, aA1, aA2)
    bp += PSTRIDE;
    // odd ky = 2kp+1: prefetch A(ky+2) (kp=17 -> ky=36, valid), compute with aB
    aA0 = *reinterpret_cast<const bf16x8*>(ap + 3072);
    aA1 = *reinterpret_cast<const bf16x8*>(ap + 3584);
    aA2 = *reinterpret_cast<const bf16x8*>(ap + 4096);
    LOAD_B_SET
    MFMA_GROUP(aB0, aB1, aB2)
    ap += 3072;
    bp += PSTRIDE;
  }
  {
    // ky = 36 tail (aA prefetched in last iteration)
    LOAD_B_SET
    MFMA_GROUP(aA0, aA1, aA2)
  }
  __syncthreads();

  // ---- epilogue: transpose C through LDS, coalesced stores
  // C row f' = (reg&3) + 8*(reg>>2) + 4*hi ; col = n (pixel y)
  float* outb = out + GAB_OFF + (size_t)(b * 54 + cin * 18) * (HH * WW);
#pragma unroll
  for (int g = 0; g < 5; ++g) {                  // f' groups [4g,4g+4), f'<20
    if (hi == (g & 1)) {
      const int rq = g >> 1;
#pragma unroll
      for (int q = 0; q < 4; ++q) {
        const int e = 4 * rq + q;
        float* crow = &cbuf[(q * 32 + n) * 33 + w];
        crow[0]  = acc0[e];
        crow[8]  = acc1[e];
        crow[16] = acc2[e];
        crow[24] = acc3[e];
      }
    }
    __syncthreads();
#pragma unroll
    for (int it = 0; it < 8; ++it) {
      int idx = tid + it * 512;                  // 4096 = 4f x 32y x 32x
      int xo = idx & 31, yo = (idx >> 5) & 31, q = idx >> 10;
      int f = 4 * g + q;
      if (f < 18)
        outb[(size_t)f * (HH * WW) + (size_t)(tileY + yo) * WW + tileX + xo] =
            cbuf[(q * 32 + yo) * 33 + xo];
    }
    __syncthreads();
  }
}

// ---------------------------------------------------------------- Haar DWT
__global__ __launch_bounds__(256) void haar_dwt_kernel(
    const float* __restrict__ x, float* __restrict__ out) {
  int idx = blockIdx.x * 256 + threadIdx.x;
  if (idx >= BB * CC * 128 * 128) return;
  int j  = idx & 127;
  int i  = (idx >> 7) & 127;
  int bc = idx >> 14;
  const float* xp = x + (size_t)bc * (HH * WW);
  float2 top = *reinterpret_cast<const float2*>(&xp[(2 * i) * WW + 2 * j]);
  float2 bot = *reinterpret_cast<const float2*>(&xp[(2 * i + 1) * WW + 2 * j]);
  float a = top.x, b = top.y, c = bot.x, d = bot.y;
  int bI = bc / 3, cI = bc % 3;
  float* op = out + DWT_OFF + ((size_t)(bI * 12 + cI * 4) * 128 + i) * 128 + j;
  op[0]     = (a + b + c + d) * 0.5f;
  op[16384] = (a + b - c - d) * 0.5f;
  op[32768] = (a - b + c - d) * 0.5f;
  op[49152] = (a - b - c + d) * 0.5f;
}

// ---------------------------------------------------------------- FFT pass A
__global__ __launch_bounds__(64) void fft_rows_kernel(
    const float* __restrict__ x, float* __restrict__ stg) {
  __shared__ float re[256], im[256], twr[128], twi[128];
  const int rowid = blockIdx.x;
  const float* xr = x + (size_t)rowid * 256;
  const int t = threadIdx.x;

#pragma unroll
  for (int q = 0; q < 2; ++q) {
    int k = t + q * 64;
    float sn, cs;
    sincosf(-2.0f * (float)M_PI * (float)k / 256.0f, &sn, &cs);
    twr[k] = cs; twi[k] = sn;
  }
#pragma unroll
  for (int q = 0; q < 4; ++q) {
    int i = t + q * 64;
    int br = __brev((unsigned)i) >> 24;
    re[br] = xr[i];
    im[br] = 0.0f;
  }
  __syncthreads();

  for (int s = 1; s <= 8; ++s) {
    int half = 1 << (s - 1);
    int sh = 8 - s;
#pragma unroll
    for (int q = 0; q < 2; ++q) {
      int j = t + q * 64;
      int g = j >> (s - 1);
      int p = j & (half - 1);
      int i1 = (g << s) + p;
      int i2 = i1 + half;
      float cs = twr[p << sh], sn = twi[p << sh];
      float r2 = re[i2], m2 = im[i2];
      float tr = r2 * cs - m2 * sn;
      float ti = r2 * sn + m2 * cs;
      float r1 = re[i1], m1 = im[i1];
      re[i2] = r1 - tr; im[i2] = m1 - ti;
      re[i1] = r1 + tr; im[i1] = m1 + ti;
    }
    __syncthreads();
  }

  float* sr = stg + (size_t)rowid * 258;
#pragma unroll
  for (int q = 0; q < 3; ++q) {
    int k = t + q * 64;
    if (k <= 128) {
      sr[2 * k]     = re[k];
      sr[2 * k + 1] = im[k];
    }
  }
}

// ---------------------------------------------------------------- FFT pass B
__global__ __launch_bounds__(64) void fft_cols_kernel(
    const float* __restrict__ stg, float* __restrict__ outf) {
  const int k  = blockIdx.x & 255;
  const int bc = blockIdx.x >> 8;
  const int b  = bc / 3;
  const int c  = bc - b * 3;
  const int t  = threadIdx.x;
  float* magp = outf + (size_t)(b * 6 + c) * (HH * WW);
  float* php  = outf + (size_t)(b * 6 + c + 3) * (HH * WW);

  if (k >= 129) {
#pragma unroll
    for (int q = 0; q < 4; ++q) {
      int u = t + q * 64;
      magp[(size_t)u * WW + k] = 0.0f;
      php[(size_t)u * WW + k]  = 0.0f;
    }
    return;
  }

  __shared__ float re[256], im[256], twr[128], twi[128];
  const float* sp = stg + (size_t)bc * (256 * 258);
#pragma unroll
  for (int q = 0; q < 2; ++q) {
    int kk = t + q * 64;
    float sn, cs;
    sincosf(-2.0f * (float)M_PI * (float)kk / 256.0f, &sn, &cs);
    twr[kk] = cs; twi[kk] = sn;
  }
#pragma unroll
  for (int q = 0; q < 4; ++q) {
    int y = t + q * 64;
    int br = __brev((unsigned)y) >> 24;
    re[br] = sp[(size_t)y * 258 + 2 * k];
    im[br] = sp[(size_t)y * 258 + 2 * k + 1];
  }
  __syncthreads();

  for (int s = 1; s <= 8; ++s) {
    int half = 1 << (s - 1);
    int sh = 8 - s;
#pragma unroll
    for (int q = 0; q < 2; ++q) {
      int j = t + q * 64;
      int g = j >> (s - 1);
      int p = j & (half - 1);
      int i1 = (g << s) + p;
      int i2 = i1 + half;
      float cs = twr[p << sh], sn = twi[p << sh];
      float r2 = re[i2], m2 = im[i2];
      float tr = r2 * cs - m2 * sn;
      float ti = r2 * sn + m2 * cs;
      float r1 = re[i1], m1 = im[i1];
      re[i2] = r1 - tr; im[i2] = m1 - ti;
      re[i1] = r1 + tr; im[i1] = m1 + ti;
    }
    __syncthreads();
  }

  const float scale = 1.0f / 256.0f;
#pragma unroll
  for (int q = 0; q < 4; ++q) {
    int u = t + q * 64;
    float r = re[u], m = im[u];
    magp[(size_t)u * WW + k] = sqrtf(r * r + m * m) * scale;
    php[(size_t)u * WW + k]  = atan2f(m, r);
  }
}

// ----------------------------------------------------------------
extern "C" void kernel_launch(void* const* d_in, const int* in_sizes, int n_in,
                              void* d_out, int out_size, void* d_ws, size_t ws_size,
                              hipStream_t stream) {
  const float* x  = (const float*)d_in[0];
  const float* wk = (const float*)d_in[1];
  float* out = (float*)d_out;

  ushort* wshc = (ushort*)(out + DWT_OFF);       // 909 KB scratch (DWT last)
  float*  stg  = out + GAB_OFF;                  // FFT staging (conv after)

  prep_wshc_kernel<<<dim3(1776), dim3(256), 0, stream>>>(wk, wshc);
  fft_rows_kernel<<<dim3(BB * CC * HH), dim3(64), 0, stream>>>(x, stg);
  fft_cols_kernel<<<dim3(BB * CC * WW), dim3(64), 0, stream>>>(stg, out + FFT_OFF);
  gabor_mfma_kernel<<<dim3(64, CC, BB), dim3(512), 0, stream>>>(x, wshc, out);
  haar_dwt_kernel<<<dim3(1536), dim3(256), 0, stream>>>(x, out);
}

// Round 8
// 169.138 us; speedup vs baseline: 1.2835x; 1.1230x over previous
//
#include <hip/hip_runtime.h>
#include <math.h>

#define BB 8
#define CC 3
#define HH 256
#define WW 256
#define KSZ 37
#define PD 18

#define DWT_OFF 0
#define GAB_OFF (8*12*128*128)                 /* 1572864 */
#define FFT_OFF (GAB_OFF + 8*54*256*256)       /* 29884416 */

#define PSTRIDE 88   /* patch row stride in bf16 elems */

#define PREP_BLOCKS 888     /* 888*512 = 454656 exactly */
#define FFTROW_BLOCKS 768   /* 6144 rows / 8 waves */
#define GAB_BLOCKS 1536
#define FFTCOL_BLOCKS 768   /* 6144 cols / 8 waves */

typedef short bf16x8 __attribute__((ext_vector_type(8)));
typedef float f32x16 __attribute__((ext_vector_type(16)));

__device__ __forceinline__ unsigned f2bf(float f) {
  unsigned u = __float_as_uint(f);
  return (u + 0x7fffu + ((u >> 16) & 1u)) >> 16;   // RNE bf16
}

// ================================================================ K1
// blocks [0,888): filter prep (coalesced layout wshc[s][ky][t][lane][8])
// blocks [888,1656): row FFTs, one wave per image row; re->mag plane
// cols 0..128, im->phase plane cols 0..128. No barriers (per-wave LDS).
__global__ __launch_bounds__(512) void fused_pre_kernel(
    const float* __restrict__ x, const float* __restrict__ wk,
    ushort* __restrict__ wshc, float* __restrict__ out) {
  __shared__ __align__(16) float smem[4352];   // re 2048 | im 2048 | tw 256
  const int g = blockIdx.x;
  const int tid = threadIdx.x;

  if (g < PREP_BLOCKS) {
    int idx = g * 512 + tid;                   // < 454656
    int j = idx & 7; int rest = idx >> 3;
    int l = rest & 63; rest >>= 6;
    int t = rest % 3; rest /= 3;
    int ky = rest % 37; int s = rest / 37;
    int m = l & 31, hi = l >> 5;
    int kk = 16 * t + 8 * hi + j - s;
    float v = 0.0f;
    if (m < 18 && kk >= 0 && kk < 37) v = wk[(m * 37 + ky) * 37 + kk];
    wshc[idx] = (ushort)f2bf(v);
    return;
  }

  // ---- row FFT
  const int w = tid >> 6;
  const int t = tid & 63;
  const int rowid = (g - PREP_BLOCKS) * 8 + w;     // [0, 6144)
  float* re  = smem + w * 256;
  float* im  = smem + 2048 + w * 256;
  float* twr = smem + 4096;
  float* twi = smem + 4224;

  // twiddles: every wave writes identical values (benign race, no barrier)
#pragma unroll
  for (int q = 0; q < 2; ++q) {
    int k = t + q * 64;
    float sn, cs;
    sincosf(-2.0f * (float)M_PI * (float)k / 256.0f, &sn, &cs);
    twr[k] = cs; twi[k] = sn;
  }

  const float* xr = x + (size_t)rowid * 256;
#pragma unroll
  for (int q = 0; q < 4; ++q) {
    int i = t + q * 64;
    int br = __brev((unsigned)i) >> 24;
    re[br] = xr[i];
    im[br] = 0.0f;
  }

  for (int s = 1; s <= 8; ++s) {
    int half = 1 << (s - 1);
    int sh = 8 - s;
#pragma unroll
    for (int q = 0; q < 2; ++q) {
      int j = t + q * 64;
      int gg = j >> (s - 1);
      int p = j & (half - 1);
      int i1 = (gg << s) + p;
      int i2 = i1 + half;
      float cs = twr[p << sh], sn = twi[p << sh];
      float r2 = re[i2], m2 = im[i2];
      float tr = r2 * cs - m2 * sn;
      float ti = r2 * sn + m2 * cs;
      float r1 = re[i1], m1 = im[i1];
      re[i2] = r1 - tr; im[i2] = m1 - ti;
      re[i1] = r1 + tr; im[i1] = m1 + ti;
    }
  }

  const int bc = rowid >> 8;                  // b*3 + c
  const int y  = rowid & 255;
  const int b  = bc / 3, c = bc - b * 3;
  float* magrow = out + FFT_OFF + (size_t)(b * 6 + c) * (HH * WW) + (size_t)y * WW;
  float* phrow  = magrow + (size_t)3 * (HH * WW);
#pragma unroll
  for (int q = 0; q < 2; ++q) {
    int k = t + q * 64;
    magrow[k] = re[k];
    phrow[k]  = im[k];
  }
  if (t == 0) { magrow[128] = re[128]; phrow[128] = im[128]; }
}

// ================================================================ K2
// blocks [0,1536): Gabor conv via MFMA (R7 structure, flattened indices)
// blocks [1536,2304): column FFTs + mag/phase, one wave per column.
#define LOAD_B_SET \
    r0 = *reinterpret_cast<const bf16x8*>(bp); \
    r1 = *reinterpret_cast<const bf16x8*>(bp + 8); \
    r2 = *reinterpret_cast<const bf16x8*>(bp + 16); \
    r3 = *reinterpret_cast<const bf16x8*>(bp + 24); \
    r4 = *reinterpret_cast<const bf16x8*>(bp + 32); \
    r5 = *reinterpret_cast<const bf16x8*>(bp + 40); \
    r6 = *reinterpret_cast<const bf16x8*>(bp + 48); \
    r7 = *reinterpret_cast<const bf16x8*>(bp + 56);
#define MFMA_GROUP(A0, A1, A2) \
    acc0 = __builtin_amdgcn_mfma_f32_32x32x16_bf16(A0, r0, acc0, 0, 0, 0); \
    acc1 = __builtin_amdgcn_mfma_f32_32x32x16_bf16(A0, r1, acc1, 0, 0, 0); \
    acc2 = __builtin_amdgcn_mfma_f32_32x32x16_bf16(A0, r2, acc2, 0, 0, 0); \
    acc3 = __builtin_amdgcn_mfma_f32_32x32x16_bf16(A0, r3, acc3, 0, 0, 0); \
    acc0 = __builtin_amdgcn_mfma_f32_32x32x16_bf16(A1, r2, acc0, 0, 0, 0); \
    acc1 = __builtin_amdgcn_mfma_f32_32x32x16_bf16(A1, r3, acc1, 0, 0, 0); \
    acc2 = __builtin_amdgcn_mfma_f32_32x32x16_bf16(A1, r4, acc2, 0, 0, 0); \
    acc3 = __builtin_amdgcn_mfma_f32_32x32x16_bf16(A1, r5, acc3, 0, 0, 0); \
    acc0 = __builtin_amdgcn_mfma_f32_32x32x16_bf16(A2, r4, acc0, 0, 0, 0); \
    acc1 = __builtin_amdgcn_mfma_f32_32x32x16_bf16(A2, r5, acc1, 0, 0, 0); \
    acc2 = __builtin_amdgcn_mfma_f32_32x32x16_bf16(A2, r6, acc2, 0, 0, 0); \
    acc3 = __builtin_amdgcn_mfma_f32_32x32x16_bf16(A2, r7, acc3, 0, 0, 0);

__global__ __launch_bounds__(512, 4) void fused_main_kernel(
    const float* __restrict__ x, const ushort* __restrict__ wshc,
    float* __restrict__ out) {
  __shared__ __align__(16) float smem[7216];
  const int g = blockIdx.x;
  const int tid = threadIdx.x;

  if (g < GAB_BLOCKS) {
    unsigned* patchU = reinterpret_cast<unsigned*>(smem);  // 68*44 uints
    float* cbuf = smem + 2992;                             // 4*32*33 floats
    const int tile = g & 63;
    const int rest = g >> 6;                               // [0,24)
    const int cin = rest % 3, b = rest / 3;
    const int tileX = (tile & 7) * 32;
    const int tileY = (tile >> 3) * 32;
    const float* xp = x + (size_t)(b * CC + cin) * (HH * WW);

    for (int idx = tid; idx < 68 * (PSTRIDE / 2); idx += 512) {
      int r = idx / (PSTRIDE / 2), dc = idx - r * (PSTRIDE / 2);
      int gy = tileY + r - PD;
      int gx0 = tileX + 2 * dc - PD;
      float v0 = 0.0f, v1 = 0.0f;
      if ((unsigned)gy < 256u) {
        if ((unsigned)gx0 < 256u)       v0 = xp[gy * WW + gx0];
        if ((unsigned)(gx0 + 1) < 256u) v1 = xp[gy * WW + gx0 + 1];
      }
      patchU[idx] = f2bf(v0) | (f2bf(v1) << 16);
    }
    __syncthreads();

    const int w  = tid >> 6;
    const int l  = tid & 63;
    const int n  = l & 31;
    const int hi = l >> 5;

    f32x16 acc0 = {0.f,0.f,0.f,0.f,0.f,0.f,0.f,0.f,0.f,0.f,0.f,0.f,0.f,0.f,0.f,0.f};
    f32x16 acc1 = acc0, acc2 = acc0, acc3 = acc0;

    const ushort* patchS = reinterpret_cast<const ushort*>(patchU);
    const ushort* ap = wshc + (size_t)w * (37 * 3 * 512) + (size_t)l * 8;
    const ushort* bp = patchS + (size_t)n * PSTRIDE + hi * 8;

    bf16x8 aA0, aA1, aA2, aB0, aB1, aB2;
    bf16x8 r0, r1, r2, r3, r4, r5, r6, r7;

    aA0 = *reinterpret_cast<const bf16x8*>(ap);
    aA1 = *reinterpret_cast<const bf16x8*>(ap + 512);
    aA2 = *reinterpret_cast<const bf16x8*>(ap + 1024);

    for (int kp = 0; kp < 18; ++kp) {
      aB0 = *reinterpret_cast<const bf16x8*>(ap + 1536);
      aB1 = *reinterpret_cast<const bf16x8*>(ap + 2048);
      aB2 = *reinterpret_cast<const bf16x8*>(ap + 2560);
      LOAD_B_SET
      MFMA_GROUP(aA0, aA1, aA2)
      bp += PSTRIDE;
      aA0 = *reinterpret_cast<const bf16x8*>(ap + 3072);
      aA1 = *reinterpret_cast<const bf16x8*>(ap + 3584);
      aA2 = *reinterpret_cast<const bf16x8*>(ap + 4096);
      LOAD_B_SET
      MFMA_GROUP(aB0, aB1, aB2)
      ap += 3072;
      bp += PSTRIDE;
    }
    {
      LOAD_B_SET
      MFMA_GROUP(aA0, aA1, aA2)
    }
    __syncthreads();

    float* outb = out + GAB_OFF + (size_t)(b * 54 + cin * 18) * (HH * WW);
#pragma unroll
    for (int gq = 0; gq < 5; ++gq) {
      if (hi == (gq & 1)) {
        const int rq = gq >> 1;
#pragma unroll
        for (int q = 0; q < 4; ++q) {
          const int e = 4 * rq + q;
          float* crow = &cbuf[(q * 32 + n) * 33 + w];
          crow[0]  = acc0[e];
          crow[8]  = acc1[e];
          crow[16] = acc2[e];
          crow[24] = acc3[e];
        }
      }
      __syncthreads();
#pragma unroll
      for (int it = 0; it < 8; ++it) {
        int idx = tid + it * 512;
        int xo = idx & 31, yo = (idx >> 5) & 31, q = idx >> 10;
        int f = 4 * gq + q;
        if (f < 18)
          outb[(size_t)f * (HH * WW) + (size_t)(tileY + yo) * WW + tileX + xo] =
              cbuf[(q * 32 + yo) * 33 + xo];
      }
      __syncthreads();
    }
    return;
  }

  // ---- column FFT + mag/phase (one wave per column; no barriers)
  const int w = tid >> 6;
  const int t = tid & 63;
  const int colid = (g - GAB_BLOCKS) * 8 + w;      // [0, 6144)
  const int bc = colid >> 8;
  const int k  = colid & 255;
  const int b  = bc / 3, c = bc - b * 3;
  float* re  = smem + w * 256;
  float* im  = smem + 2048 + w * 256;
  float* twr = smem + 4096;
  float* twi = smem + 4224;

#pragma unroll
  for (int q = 0; q < 2; ++q) {
    int kk = t + q * 64;
    float sn, cs;
    sincosf(-2.0f * (float)M_PI * (float)kk / 256.0f, &sn, &cs);
    twr[kk] = cs; twi[kk] = sn;
  }

  float* magp = out + FFT_OFF + (size_t)(b * 6 + c) * (HH * WW);
  float* php  = magp + (size_t)3 * (HH * WW);
  const bool live = (k < 129);
#pragma unroll
  for (int q = 0; q < 4; ++q) {
    int y = t + q * 64;
    int br = __brev((unsigned)y) >> 24;
    re[br] = live ? magp[(size_t)y * WW + k] : 0.0f;
    im[br] = live ? php[(size_t)y * WW + k]  : 0.0f;
  }

  for (int s = 1; s <= 8; ++s) {
    int half = 1 << (s - 1);
    int sh = 8 - s;
#pragma unroll
    for (int q = 0; q < 2; ++q) {
      int j = t + q * 64;
      int gg = j >> (s - 1);
      int p = j & (half - 1);
      int i1 = (gg << s) + p;
      int i2 = i1 + half;
      float cs = twr[p << sh], sn = twi[p << sh];
      float r2 = re[i2], m2 = im[i2];
      float tr = r2 * cs - m2 * sn;
      float ti = r2 * sn + m2 * cs;
      float r1 = re[i1], m1 = im[i1];
      re[i2] = r1 - tr; im[i2] = m1 - ti;
      re[i1] = r1 + tr; im[i1] = m1 + ti;
    }
  }

  const float scale = 1.0f / 256.0f;   // ortho: /sqrt(256*256)
#pragma unroll
  for (int q = 0; q < 4; ++q) {
    int u = t + q * 64;
    float r = re[u], m = im[u];
    magp[(size_t)u * WW + k] = sqrtf(r * r + m * m) * scale;
    php[(size_t)u * WW + k]  = atan2f(m, r);
  }
}

// ================================================================ K3: DWT
__global__ __launch_bounds__(256) void haar_dwt_kernel(
    const float* __restrict__ x, float* __restrict__ out) {
  int idx = blockIdx.x * 256 + threadIdx.x;
  if (idx >= BB * CC * 128 * 128) return;
  int j  = idx & 127;
  int i  = (idx >> 7) & 127;
  int bc = idx >> 14;
  const float* xp = x + (size_t)bc * (HH * WW);
  float2 top = *reinterpret_cast<const float2*>(&xp[(2 * i) * WW + 2 * j]);
  float2 bot = *reinterpret_cast<const float2*>(&xp[(2 * i + 1) * WW + 2 * j]);
  float a = top.x, b = top.y, c = bot.x, d = bot.y;
  int bI = bc / 3, cI = bc % 3;
  float* op = out + DWT_OFF + ((size_t)(bI * 12 + cI * 4) * 128 + i) * 128 + j;
  op[0]     = (a + b + c + d) * 0.5f;
  op[16384] = (a + b - c - d) * 0.5f;
  op[32768] = (a - b + c - d) * 0.5f;
  op[49152] = (a - b - c + d) * 0.5f;
}

// ----------------------------------------------------------------
extern "C" void kernel_launch(void* const* d_in, const int* in_sizes, int n_in,
                              void* d_out, int out_size, void* d_ws, size_t ws_size,
                              hipStream_t stream) {
  const float* x  = (const float*)d_in[0];
  const float* wk = (const float*)d_in[1];
  float* out = (float*)d_out;

  // wshc scratch lives in the DWT output region; DWT (K3) runs last.
  ushort* wshc = (ushort*)(out + DWT_OFF);       // 909 KB

  fused_pre_kernel<<<dim3(PREP_BLOCKS + FFTROW_BLOCKS), dim3(512), 0, stream>>>(
      x, wk, wshc, out);
  fused_main_kernel<<<dim3(GAB_BLOCKS + FFTCOL_BLOCKS), dim3(512), 0, stream>>>(
      x, wshc, out);
  haar_dwt_kernel<<<dim3(1536), dim3(256), 0, stream>>>(x, out);
}